// Round 10
// baseline (61.753 us; speedup 1.0000x reference)
//
#include <hip/hip_runtime.h>
#include <math.h>

#define BB 64
#define ZZ 8
#define UU 8
#define PP 128
#define XX 64
#define HH 512

typedef float f32x4 __attribute__((ext_vector_type(4)));
typedef float f32x2 __attribute__((ext_vector_type(2)));

__device__ __forceinline__ float elu(float v) {
    return v > 0.f ? v : (expf(v) - 1.f);
}

// ---------------------------------------------------------------------------
// One 128-col chunk of a GEMV layer: out[0..128) = act(hs @ W[:, c0+..] + bias).
// hs = full input row in LDS (K floats). 256 threads = 32 f32x4 column
// groups x 8 K-slices; red padded (33-stride) to kill the reduce conflict.
// ---------------------------------------------------------------------------
template<int K, bool ELU>
__device__ __forceinline__ void chunk_gemv(
    const float* __restrict__ hs, const float* __restrict__ W,
    const float* __restrict__ biasC0, float* __restrict__ out,
    int N, int c0, int tid, f32x4* __restrict__ red) {
    constexpr int KPER = K / 8;
    const int g    = tid & 31;
    const int ks   = tid >> 5;
    const int kBeg = ks * KPER;
    const float* Wp = W + (size_t)kBeg * N + c0 + g * 4;

    f32x4 acc = {0.f, 0.f, 0.f, 0.f};
    #pragma unroll 8
    for (int k = 0; k < KPER; ++k) {
        const f32x4 w = *(const f32x4*)(Wp + (size_t)k * N);
        const float s = hs[kBeg + k];
        acc.x = fmaf(s, w.x, acc.x);
        acc.y = fmaf(s, w.y, acc.y);
        acc.z = fmaf(s, w.z, acc.z);
        acc.w = fmaf(s, w.w, acc.w);
    }
    red[ks * 33 + g] = acc;
    __syncthreads();

    if (tid < 32) {
        f32x4 a = red[tid];
        #pragma unroll
        for (int s2 = 1; s2 < 8; ++s2) {
            const f32x4 b = red[s2 * 33 + tid];
            a.x += b.x; a.y += b.y; a.z += b.z; a.w += b.w;
        }
        const f32x4 bb = *(const f32x4*)(biasC0 + tid * 4);
        a.x += bb.x; a.y += bb.y; a.z += bb.z; a.w += bb.w;
        if (ELU) { a.x = elu(a.x); a.y = elu(a.y); a.z = elu(a.z); a.w = elu(a.w); }
        *(f32x4*)(out + tid * 4) = a;
    }
    __syncthreads();
}

// ---------------------------------------------------------------------------
// Layers 1+2 fused: grid (4, 64). Each block recomputes the full h1 row
// (W1 is 128 KB, L2-shared -> ~free), then its 128-col chunk of h2.
// ---------------------------------------------------------------------------
__global__ __launch_bounds__(256) void l12_kernel(
    const float* __restrict__ x,
    const float* __restrict__ W1, const float* __restrict__ b1,
    const float* __restrict__ W2, const float* __restrict__ b2,
    float* __restrict__ h2buf) {
    __shared__ __align__(16) float xs[XX];
    __shared__ __align__(16) float hs[HH];
    __shared__ __align__(16) f32x4 red[8 * 33];

    const int tid = threadIdx.x;
    const int r   = blockIdx.y;
    const int c0  = blockIdx.x * 128;

    if (tid < XX) xs[tid] = x[(size_t)r * XX + tid];
    __syncthreads();

    {   // h1 full row: thread tid -> cols 2tid, 2tid+1
        const f32x2* W = (const f32x2*)W1;   // [XX][HH/2]
        f32x2 a0 = {0.f, 0.f}, a1 = {0.f, 0.f};
        #pragma unroll 8
        for (int k = 0; k < XX; k += 2) {
            const f32x2 w0 = W[(k + 0) * (HH / 2) + tid];
            const f32x2 w1 = W[(k + 1) * (HH / 2) + tid];
            const float s0 = xs[k + 0], s1 = xs[k + 1];
            a0.x = fmaf(s0, w0.x, a0.x); a0.y = fmaf(s0, w0.y, a0.y);
            a1.x = fmaf(s1, w1.x, a1.x); a1.y = fmaf(s1, w1.y, a1.y);
        }
        const f32x2 bb = ((const f32x2*)b1)[tid];
        hs[2 * tid + 0] = elu(a0.x + a1.x + bb.x);
        hs[2 * tid + 1] = elu(a0.y + a1.y + bb.y);
    }
    __syncthreads();

    chunk_gemv<HH, true>(hs, W2, b2 + c0, h2buf + (size_t)r * HH + c0, HH, c0, tid, red);
}

// ---------------------------------------------------------------------------
// Layer 3 + partial-phi: grid (4, 64). Block (c,r) stages the h2 row,
// computes h3 cols [c*128,(c+1)*128) into LDS (never hits global), then
// pphi[c][r][:] = h3_chunk @ W4[c*128:(c+1)*128, :]  (64 KB of W4/block).
// ---------------------------------------------------------------------------
__global__ __launch_bounds__(256) void l34_kernel(
    const float* __restrict__ h2buf,
    const float* __restrict__ W3, const float* __restrict__ b3,
    const float* __restrict__ W4,
    float* __restrict__ pphi) {
    __shared__ __align__(16) float hs[HH];
    __shared__ __align__(16) float hs3[128];
    __shared__ __align__(16) f32x4 red[8 * 33];
    __shared__ float red2[2][128];

    const int tid = threadIdx.x;
    const int r   = blockIdx.y;
    const int c   = blockIdx.x;
    const int c0  = c * 128;

    ((f32x2*)hs)[tid] = ((const f32x2*)(h2buf + (size_t)r * HH))[tid];
    __syncthreads();

    chunk_gemv<HH, true>(hs, W3, b3 + c0, hs3, HH, c0, tid, red);

    {   // partial phi: 2 k-slices x 128 cols
        const int j    = tid & 127;
        const int half = tid >> 7;
        const int kBeg = half * 64;
        const float* Wp = W4 + (size_t)(c0 + kBeg) * PP + j;
        float acc = 0.f;
        #pragma unroll 8
        for (int k = 0; k < 64; ++k)
            acc = fmaf(hs3[kBeg + k], Wp[(size_t)k * PP], acc);
        red2[half][j] = acc;
    }
    __syncthreads();
    if (tid < 128)
        pphi[((size_t)c * BB + r) * PP + tid] = red2[0][tid] + red2[1][tid];
}

// ---------------------------------------------------------------------------
// Bilinear over Linv. FOUR consecutive (b,z,u) per block (all share b -> one
// phi prologue serves 4 matrices). Nontemporal loads (zero reuse). 4
// independent load streams per thread -> ~2x deeper vmcnt window than the
// 2-matrix version (launch_bounds(256,2) allows the VGPR budget); 1024
// prologues/epilogues instead of 2048.
// ---------------------------------------------------------------------------
__global__ __launch_bounds__(256, 2) void bilinear_kernel(
    const float* __restrict__ Linv, const float* __restrict__ Q,
    const float* __restrict__ pphi, const float* __restrict__ b4,
    const float* __restrict__ logSigEps,
    float* __restrict__ out_mu, float* __restrict__ out_cov) {
    __shared__ __align__(16) float Ps[PP];
    __shared__ __align__(16) float Qs[4][PP];
    __shared__ float red[32];

    const int bzu0 = blockIdx.x * 4;   // 4 consecutive -> same b (and z)
    const int b    = bzu0 >> 6;
    const int tid  = threadIdx.x;

    if (tid < 128) {
        Ps[tid] = b4[tid]
                + pphi[((size_t)0 * BB + b) * PP + tid]
                + pphi[((size_t)1 * BB + b) * PP + tid]
                + pphi[((size_t)2 * BB + b) * PP + tid]
                + pphi[((size_t)3 * BB + b) * PP + tid];
    } else {
        const int m = (tid - 128) >> 5;         // matrix 0..3
        const int t = tid & 31;
        ((f32x4*)Qs[m])[t] = ((const f32x4*)(Q + (size_t)(bzu0 + m) * PP))[t];
    }
    __syncthreads();

    const int j0 = (tid & 31) << 2;             // constant across iterations
    const f32x4 q0 = *(const f32x4*)(Qs[0] + j0);
    const f32x4 q1 = *(const f32x4*)(Qs[1] + j0);
    const f32x4 q2 = *(const f32x4*)(Qs[2] + j0);
    const f32x4 q3 = *(const f32x4*)(Qs[3] + j0);
    const f32x4 p  = *(const f32x4*)(Ps + j0);

    const f32x4* LA = (const f32x4*)(Linv + (size_t)(bzu0 + 0) * (PP * PP));
    const f32x4* LB = (const f32x4*)(Linv + (size_t)(bzu0 + 1) * (PP * PP));
    const f32x4* LC = (const f32x4*)(Linv + (size_t)(bzu0 + 2) * (PP * PP));
    const f32x4* LD = (const f32x4*)(Linv + (size_t)(bzu0 + 3) * (PP * PP));

    float accM0 = 0.f, accS0 = 0.f, accM1 = 0.f, accS1 = 0.f;
    float accM2 = 0.f, accS2 = 0.f, accM3 = 0.f, accS3 = 0.f;
    #pragma unroll
    for (int it = 0; it < 16; ++it) {
        const int f = it * 256 + tid;           // float4 index within a matrix
        const f32x4 La = __builtin_nontemporal_load(LA + f);
        const f32x4 Lb = __builtin_nontemporal_load(LB + f);
        const f32x4 Lc = __builtin_nontemporal_load(LC + f);
        const f32x4 Ld = __builtin_nontemporal_load(LD + f);
        const float pi = Ps[f >> 5];            // 2 addrs/wave -> broadcast
        const float sm0 = La.x * q0.x + La.y * q0.y + La.z * q0.z + La.w * q0.w;
        const float sp0 = La.x * p.x  + La.y * p.y  + La.z * p.z  + La.w * p.w;
        const float sm1 = Lb.x * q1.x + Lb.y * q1.y + Lb.z * q1.z + Lb.w * q1.w;
        const float sp1 = Lb.x * p.x  + Lb.y * p.y  + Lb.z * p.z  + Lb.w * p.w;
        const float sm2 = Lc.x * q2.x + Lc.y * q2.y + Lc.z * q2.z + Lc.w * q2.w;
        const float sp2 = Lc.x * p.x  + Lc.y * p.y  + Lc.z * p.z  + Lc.w * p.w;
        const float sm3 = Ld.x * q3.x + Ld.y * q3.y + Ld.z * q3.z + Ld.w * q3.w;
        const float sp3 = Ld.x * p.x  + Ld.y * p.y  + Ld.z * p.z  + Ld.w * p.w;
        accM0 = fmaf(pi, sm0, accM0);  accS0 = fmaf(pi, sp0, accS0);
        accM1 = fmaf(pi, sm1, accM1);  accS1 = fmaf(pi, sp1, accS1);
        accM2 = fmaf(pi, sm2, accM2);  accS2 = fmaf(pi, sp2, accS2);
        accM3 = fmaf(pi, sm3, accM3);  accS3 = fmaf(pi, sp3, accS3);
    }

    for (int off = 32; off; off >>= 1) {
        accM0 += __shfl_down(accM0, off, 64);
        accS0 += __shfl_down(accS0, off, 64);
        accM1 += __shfl_down(accM1, off, 64);
        accS1 += __shfl_down(accS1, off, 64);
        accM2 += __shfl_down(accM2, off, 64);
        accS2 += __shfl_down(accS2, off, 64);
        accM3 += __shfl_down(accM3, off, 64);
        accS3 += __shfl_down(accS3, off, 64);
    }
    const int wid = tid >> 6;
    if ((tid & 63) == 0) {
        red[wid]      = accM0; red[4 + wid]  = accS0;
        red[8 + wid]  = accM1; red[12 + wid] = accS1;
        red[16 + wid] = accM2; red[20 + wid] = accS2;
        red[24 + wid] = accM3; red[28 + wid] = accS3;
    }
    __syncthreads();
    if (tid < 4) {
        const float m = (red[8 * tid + 0] + red[8 * tid + 1])
                      + (red[8 * tid + 2] + red[8 * tid + 3]);
        const float s = (red[8 * tid + 4] + red[8 * tid + 5])
                      + (red[8 * tid + 6] + red[8 * tid + 7]);
        const int bzu = bzu0 + tid;
        out_mu[bzu]  = m;
        out_cov[bzu] = expf(logSigEps[bzu & 7]) * (1.f + s);
    }
}

extern "C" void kernel_launch(void* const* d_in, const int* in_sizes, int n_in,
                              void* d_out, int out_size, void* d_ws, size_t ws_size,
                              hipStream_t stream) {
    const float* x         = (const float*)d_in[0];
    const float* Linv      = (const float*)d_in[1];
    const float* Q         = (const float*)d_in[2];
    const float* W1        = (const float*)d_in[3];
    const float* b1        = (const float*)d_in[4];
    const float* W2        = (const float*)d_in[5];
    const float* b2        = (const float*)d_in[6];
    const float* W3        = (const float*)d_in[7];
    const float* b3        = (const float*)d_in[8];
    const float* W4        = (const float*)d_in[9];
    const float* b4        = (const float*)d_in[10];
    const float* logSigEps = (const float*)d_in[11];

    float* ws   = (float*)d_ws;
    float* h2   = ws;                 // 64*512
    float* pphi = ws + BB * HH;       // 4*64*128

    l12_kernel<<<dim3(4, BB), 256, 0, stream>>>(x, W1, b1, W2, b2, h2);
    l34_kernel<<<dim3(4, BB), 256, 0, stream>>>(h2, W3, b3, W4, pphi);

    float* out_mu  = (float*)d_out;          // (B,Z,U,1) = 4096 floats
    float* out_cov = out_mu + BB * ZZ * UU;  // (B,Z,U)   = 4096 floats

    bilinear_kernel<<<(BB * ZZ * UU) / 4, 256, 0, stream>>>(
        Linv, Q, pphi, b4, logSigEps, out_mu, out_cov);
}

// Round 11
// 61.222 us; speedup vs baseline: 1.0087x; 1.0087x over previous
//
#include <hip/hip_runtime.h>
#include <math.h>

#define BB 64
#define ZZ 8
#define UU 8
#define PP 128
#define XX 64
#define HH 512

typedef float f32x4 __attribute__((ext_vector_type(4)));
typedef float f32x2 __attribute__((ext_vector_type(2)));

__device__ __forceinline__ float elu(float v) {
    return v > 0.f ? v : (expf(v) - 1.f);
}

// ---------------------------------------------------------------------------
// One 128-col chunk of a GEMV layer: out[0..128) = act(hs @ W[:, c0+..] + bias).
// hs = full input row in LDS (K floats). 256 threads = 32 f32x4 column
// groups x 8 K-slices; red padded (33-stride) to kill the reduce conflict.
// ---------------------------------------------------------------------------
template<int K, bool ELU>
__device__ __forceinline__ void chunk_gemv(
    const float* __restrict__ hs, const float* __restrict__ W,
    const float* __restrict__ biasC0, float* __restrict__ out,
    int N, int c0, int tid, f32x4* __restrict__ red) {
    constexpr int KPER = K / 8;
    const int g    = tid & 31;
    const int ks   = tid >> 5;
    const int kBeg = ks * KPER;
    const float* Wp = W + (size_t)kBeg * N + c0 + g * 4;

    f32x4 acc = {0.f, 0.f, 0.f, 0.f};
    #pragma unroll 8
    for (int k = 0; k < KPER; ++k) {
        const f32x4 w = *(const f32x4*)(Wp + (size_t)k * N);
        const float s = hs[kBeg + k];
        acc.x = fmaf(s, w.x, acc.x);
        acc.y = fmaf(s, w.y, acc.y);
        acc.z = fmaf(s, w.z, acc.z);
        acc.w = fmaf(s, w.w, acc.w);
    }
    red[ks * 33 + g] = acc;
    __syncthreads();

    if (tid < 32) {
        f32x4 a = red[tid];
        #pragma unroll
        for (int s2 = 1; s2 < 8; ++s2) {
            const f32x4 b = red[s2 * 33 + tid];
            a.x += b.x; a.y += b.y; a.z += b.z; a.w += b.w;
        }
        const f32x4 bb = *(const f32x4*)(biasC0 + tid * 4);
        a.x += bb.x; a.y += bb.y; a.z += bb.z; a.w += bb.w;
        if (ELU) { a.x = elu(a.x); a.y = elu(a.y); a.z = elu(a.z); a.w = elu(a.w); }
        *(f32x4*)(out + tid * 4) = a;
    }
    __syncthreads();
}

// ---------------------------------------------------------------------------
// Layers 1+2 fused: grid (4, 64). Each block recomputes the full h1 row
// (W1 is 128 KB, L2-shared -> ~free), then its 128-col chunk of h2.
// ---------------------------------------------------------------------------
__global__ __launch_bounds__(256) void l12_kernel(
    const float* __restrict__ x,
    const float* __restrict__ W1, const float* __restrict__ b1,
    const float* __restrict__ W2, const float* __restrict__ b2,
    float* __restrict__ h2buf) {
    __shared__ __align__(16) float xs[XX];
    __shared__ __align__(16) float hs[HH];
    __shared__ __align__(16) f32x4 red[8 * 33];

    const int tid = threadIdx.x;
    const int r   = blockIdx.y;
    const int c0  = blockIdx.x * 128;

    if (tid < XX) xs[tid] = x[(size_t)r * XX + tid];
    __syncthreads();

    {   // h1 full row: thread tid -> cols 2tid, 2tid+1
        const f32x2* W = (const f32x2*)W1;   // [XX][HH/2]
        f32x2 a0 = {0.f, 0.f}, a1 = {0.f, 0.f};
        #pragma unroll 8
        for (int k = 0; k < XX; k += 2) {
            const f32x2 w0 = W[(k + 0) * (HH / 2) + tid];
            const f32x2 w1 = W[(k + 1) * (HH / 2) + tid];
            const float s0 = xs[k + 0], s1 = xs[k + 1];
            a0.x = fmaf(s0, w0.x, a0.x); a0.y = fmaf(s0, w0.y, a0.y);
            a1.x = fmaf(s1, w1.x, a1.x); a1.y = fmaf(s1, w1.y, a1.y);
        }
        const f32x2 bb = ((const f32x2*)b1)[tid];
        hs[2 * tid + 0] = elu(a0.x + a1.x + bb.x);
        hs[2 * tid + 1] = elu(a0.y + a1.y + bb.y);
    }
    __syncthreads();

    chunk_gemv<HH, true>(hs, W2, b2 + c0, h2buf + (size_t)r * HH + c0, HH, c0, tid, red);
}

// ---------------------------------------------------------------------------
// Layer 3 + partial-phi: grid (4, 64). Block (c,r) stages the h2 row,
// computes h3 cols [c*128,(c+1)*128) into LDS (never hits global), then
// pphi[c][r][:] = h3_chunk @ W4[c*128:(c+1)*128, :]  (64 KB of W4/block).
// ---------------------------------------------------------------------------
__global__ __launch_bounds__(256) void l34_kernel(
    const float* __restrict__ h2buf,
    const float* __restrict__ W3, const float* __restrict__ b3,
    const float* __restrict__ W4,
    float* __restrict__ pphi) {
    __shared__ __align__(16) float hs[HH];
    __shared__ __align__(16) float hs3[128];
    __shared__ __align__(16) f32x4 red[8 * 33];
    __shared__ float red2[2][128];

    const int tid = threadIdx.x;
    const int r   = blockIdx.y;
    const int c   = blockIdx.x;
    const int c0  = c * 128;

    ((f32x2*)hs)[tid] = ((const f32x2*)(h2buf + (size_t)r * HH))[tid];
    __syncthreads();

    chunk_gemv<HH, true>(hs, W3, b3 + c0, hs3, HH, c0, tid, red);

    {   // partial phi: 2 k-slices x 128 cols
        const int j    = tid & 127;
        const int half = tid >> 7;
        const int kBeg = half * 64;
        const float* Wp = W4 + (size_t)(c0 + kBeg) * PP + j;
        float acc = 0.f;
        #pragma unroll 8
        for (int k = 0; k < 64; ++k)
            acc = fmaf(hs3[kBeg + k], Wp[(size_t)k * PP], acc);
        red2[half][j] = acc;
    }
    __syncthreads();
    if (tid < 128)
        pphi[((size_t)c * BB + r) * PP + tid] = red2[0][tid] + red2[1][tid];
}

// ---------------------------------------------------------------------------
// Bilinear over Linv. TWO consecutive (b,z,u) per block (shared b -> shared
// phi prologue). A/B this round: PLAIN loads (no nontemporal) -- nt skips
// L2 entirely; the L2 may be a useful burst-smoothing stage even for a
// zero-reuse stream. Everything else identical to the best config (R8).
// ---------------------------------------------------------------------------
__global__ __launch_bounds__(256) void bilinear_kernel(
    const float* __restrict__ Linv, const float* __restrict__ Q,
    const float* __restrict__ pphi, const float* __restrict__ b4,
    const float* __restrict__ logSigEps,
    float* __restrict__ out_mu, float* __restrict__ out_cov) {
    __shared__ __align__(16) float Ps[PP];
    __shared__ __align__(16) float Qs0[PP];
    __shared__ __align__(16) float Qs1[PP];
    __shared__ float red[16];

    const int bzu0 = blockIdx.x * 2;   // both matrices share b (64 % 2 == 0)
    const int bzu1 = bzu0 + 1;
    const int b    = bzu0 >> 6;
    const int tid  = threadIdx.x;

    if (tid < 128) {
        Ps[tid] = b4[tid]
                + pphi[((size_t)0 * BB + b) * PP + tid]
                + pphi[((size_t)1 * BB + b) * PP + tid]
                + pphi[((size_t)2 * BB + b) * PP + tid]
                + pphi[((size_t)3 * BB + b) * PP + tid];
    } else if (tid < 160) {
        ((f32x4*)Qs0)[tid - 128] = ((const f32x4*)(Q + (size_t)bzu0 * PP))[tid - 128];
    } else if (tid < 192) {
        ((f32x4*)Qs1)[tid - 160] = ((const f32x4*)(Q + (size_t)bzu1 * PP))[tid - 160];
    }
    __syncthreads();

    const int j0 = (tid & 31) << 2;            // constant across iterations
    const f32x4 q0 = *(const f32x4*)(Qs0 + j0);
    const f32x4 q1 = *(const f32x4*)(Qs1 + j0);
    const f32x4 p  = *(const f32x4*)(Ps + j0);

    const f32x4* LA = (const f32x4*)(Linv + (size_t)bzu0 * (PP * PP));
    const f32x4* LB = (const f32x4*)(Linv + (size_t)bzu1 * (PP * PP));
    float accM0 = 0.f, accS0 = 0.f, accM1 = 0.f, accS1 = 0.f;
    #pragma unroll
    for (int it = 0; it < 16; ++it) {
        const int f = it * 256 + tid;          // float4 index within a matrix
        const f32x4 La = LA[f];
        const f32x4 Lb = LB[f];
        const float pi = Ps[f >> 5];           // LDS broadcast (2 addrs/wave)
        const float sm0 = La.x * q0.x + La.y * q0.y + La.z * q0.z + La.w * q0.w;
        const float sp0 = La.x * p.x  + La.y * p.y  + La.z * p.z  + La.w * p.w;
        const float sm1 = Lb.x * q1.x + Lb.y * q1.y + Lb.z * q1.z + Lb.w * q1.w;
        const float sp1 = Lb.x * p.x  + Lb.y * p.y  + Lb.z * p.z  + Lb.w * p.w;
        accM0 = fmaf(pi, sm0, accM0);
        accS0 = fmaf(pi, sp0, accS0);
        accM1 = fmaf(pi, sm1, accM1);
        accS1 = fmaf(pi, sp1, accS1);
    }

    for (int off = 32; off; off >>= 1) {
        accM0 += __shfl_down(accM0, off, 64);
        accS0 += __shfl_down(accS0, off, 64);
        accM1 += __shfl_down(accM1, off, 64);
        accS1 += __shfl_down(accS1, off, 64);
    }
    const int wid = tid >> 6;
    if ((tid & 63) == 0) {
        red[wid]      = accM0; red[4 + wid]  = accS0;
        red[8 + wid]  = accM1; red[12 + wid] = accS1;
    }
    __syncthreads();
    if (tid == 0) {
        const float m0 = (red[0] + red[1]) + (red[2] + red[3]);
        const float s0 = (red[4] + red[5]) + (red[6] + red[7]);
        const float m1 = (red[8] + red[9]) + (red[10] + red[11]);
        const float s1 = (red[12] + red[13]) + (red[14] + red[15]);
        out_mu[bzu0]  = m0;
        out_cov[bzu0] = expf(logSigEps[bzu0 & 7]) * (1.f + s0);
        out_mu[bzu1]  = m1;
        out_cov[bzu1] = expf(logSigEps[bzu1 & 7]) * (1.f + s1);
    }
}

extern "C" void kernel_launch(void* const* d_in, const int* in_sizes, int n_in,
                              void* d_out, int out_size, void* d_ws, size_t ws_size,
                              hipStream_t stream) {
    const float* x         = (const float*)d_in[0];
    const float* Linv      = (const float*)d_in[1];
    const float* Q         = (const float*)d_in[2];
    const float* W1        = (const float*)d_in[3];
    const float* b1        = (const float*)d_in[4];
    const float* W2        = (const float*)d_in[5];
    const float* b2        = (const float*)d_in[6];
    const float* W3        = (const float*)d_in[7];
    const float* b3        = (const float*)d_in[8];
    const float* W4        = (const float*)d_in[9];
    const float* b4        = (const float*)d_in[10];
    const float* logSigEps = (const float*)d_in[11];

    float* ws   = (float*)d_ws;
    float* h2   = ws;                 // 64*512
    float* pphi = ws + BB * HH;       // 4*64*128

    l12_kernel<<<dim3(4, BB), 256, 0, stream>>>(x, W1, b1, W2, b2, h2);
    l34_kernel<<<dim3(4, BB), 256, 0, stream>>>(h2, W3, b3, W4, pphi);

    float* out_mu  = (float*)d_out;          // (B,Z,U,1) = 4096 floats
    float* out_cov = out_mu + BB * ZZ * UU;  // (B,Z,U)   = 4096 floats

    bilinear_kernel<<<(BB * ZZ * UU) / 2, 256, 0, stream>>>(
        Linv, Q, pphi, b4, logSigEps, out_mu, out_cov);
}

// Round 12
// 59.179 us; speedup vs baseline: 1.0435x; 1.0345x over previous
//
#include <hip/hip_runtime.h>
#include <math.h>

#define BB 64
#define ZZ 8
#define UU 8
#define PP 128
#define XX 64
#define HH 512

typedef float f32x4 __attribute__((ext_vector_type(4)));
typedef float f32x2 __attribute__((ext_vector_type(2)));

__device__ __forceinline__ float elu(float v) {
    return v > 0.f ? v : (expf(v) - 1.f);
}

// ---------------------------------------------------------------------------
// One 128-col chunk of a GEMV layer: out[0..128) = act(hs @ W[:, c0+..] + bias).
// hs = full input row in LDS (K floats). 256 threads = 32 f32x4 column
// groups x 8 K-slices; red padded (33-stride) to kill the reduce conflict.
// ---------------------------------------------------------------------------
template<int K, bool ELU>
__device__ __forceinline__ void chunk_gemv(
    const float* __restrict__ hs, const float* __restrict__ W,
    const float* __restrict__ biasC0, float* __restrict__ out,
    int N, int c0, int tid, f32x4* __restrict__ red) {
    constexpr int KPER = K / 8;
    const int g    = tid & 31;
    const int ks   = tid >> 5;
    const int kBeg = ks * KPER;
    const float* Wp = W + (size_t)kBeg * N + c0 + g * 4;

    f32x4 acc = {0.f, 0.f, 0.f, 0.f};
    #pragma unroll 8
    for (int k = 0; k < KPER; ++k) {
        const f32x4 w = *(const f32x4*)(Wp + (size_t)k * N);
        const float s = hs[kBeg + k];
        acc.x = fmaf(s, w.x, acc.x);
        acc.y = fmaf(s, w.y, acc.y);
        acc.z = fmaf(s, w.z, acc.z);
        acc.w = fmaf(s, w.w, acc.w);
    }
    red[ks * 33 + g] = acc;
    __syncthreads();

    if (tid < 32) {
        f32x4 a = red[tid];
        #pragma unroll
        for (int s2 = 1; s2 < 8; ++s2) {
            const f32x4 b = red[s2 * 33 + tid];
            a.x += b.x; a.y += b.y; a.z += b.z; a.w += b.w;
        }
        const f32x4 bb = *(const f32x4*)(biasC0 + tid * 4);
        a.x += bb.x; a.y += bb.y; a.z += bb.z; a.w += bb.w;
        if (ELU) { a.x = elu(a.x); a.y = elu(a.y); a.z = elu(a.z); a.w = elu(a.w); }
        *(f32x4*)(out + tid * 4) = a;
    }
    __syncthreads();
}

// ---------------------------------------------------------------------------
// Layers 1+2 fused: grid (4, 64). Each block recomputes the full h1 row
// (W1 is 128 KB, L2-shared -> ~free), then its 128-col chunk of h2.
// ---------------------------------------------------------------------------
__global__ __launch_bounds__(256) void l12_kernel(
    const float* __restrict__ x,
    const float* __restrict__ W1, const float* __restrict__ b1,
    const float* __restrict__ W2, const float* __restrict__ b2,
    float* __restrict__ h2buf) {
    __shared__ __align__(16) float xs[XX];
    __shared__ __align__(16) float hs[HH];
    __shared__ __align__(16) f32x4 red[8 * 33];

    const int tid = threadIdx.x;
    const int r   = blockIdx.y;
    const int c0  = blockIdx.x * 128;

    if (tid < XX) xs[tid] = x[(size_t)r * XX + tid];
    __syncthreads();

    {   // h1 full row: thread tid -> cols 2tid, 2tid+1
        const f32x2* W = (const f32x2*)W1;   // [XX][HH/2]
        f32x2 a0 = {0.f, 0.f}, a1 = {0.f, 0.f};
        #pragma unroll 8
        for (int k = 0; k < XX; k += 2) {
            const f32x2 w0 = W[(k + 0) * (HH / 2) + tid];
            const f32x2 w1 = W[(k + 1) * (HH / 2) + tid];
            const float s0 = xs[k + 0], s1 = xs[k + 1];
            a0.x = fmaf(s0, w0.x, a0.x); a0.y = fmaf(s0, w0.y, a0.y);
            a1.x = fmaf(s1, w1.x, a1.x); a1.y = fmaf(s1, w1.y, a1.y);
        }
        const f32x2 bb = ((const f32x2*)b1)[tid];
        hs[2 * tid + 0] = elu(a0.x + a1.x + bb.x);
        hs[2 * tid + 1] = elu(a0.y + a1.y + bb.y);
    }
    __syncthreads();

    chunk_gemv<HH, true>(hs, W2, b2 + c0, h2buf + (size_t)r * HH + c0, HH, c0, tid, red);
}

// ---------------------------------------------------------------------------
// Layer 3 + partial-phi: grid (4, 64). Block (c,r) stages the h2 row,
// computes h3 cols [c*128,(c+1)*128) into LDS (never hits global), then
// pphi[c][r][:] = h3_chunk @ W4[c*128:(c+1)*128, :]  (64 KB of W4/block).
// ---------------------------------------------------------------------------
__global__ __launch_bounds__(256) void l34_kernel(
    const float* __restrict__ h2buf,
    const float* __restrict__ W3, const float* __restrict__ b3,
    const float* __restrict__ W4,
    float* __restrict__ pphi) {
    __shared__ __align__(16) float hs[HH];
    __shared__ __align__(16) float hs3[128];
    __shared__ __align__(16) f32x4 red[8 * 33];
    __shared__ float red2[2][128];

    const int tid = threadIdx.x;
    const int r   = blockIdx.y;
    const int c   = blockIdx.x;
    const int c0  = c * 128;

    ((f32x2*)hs)[tid] = ((const f32x2*)(h2buf + (size_t)r * HH))[tid];
    __syncthreads();

    chunk_gemv<HH, true>(hs, W3, b3 + c0, hs3, HH, c0, tid, red);

    {   // partial phi: 2 k-slices x 128 cols
        const int j    = tid & 127;
        const int half = tid >> 7;
        const int kBeg = half * 64;
        const float* Wp = W4 + (size_t)(c0 + kBeg) * PP + j;
        float acc = 0.f;
        #pragma unroll 8
        for (int k = 0; k < 64; ++k)
            acc = fmaf(hs3[kBeg + k], Wp[(size_t)k * PP], acc);
        red2[half][j] = acc;
    }
    __syncthreads();
    if (tid < 128)
        pphi[((size_t)c * BB + r) * PP + tid] = red2[0][tid] + red2[1][tid];
}

// ---------------------------------------------------------------------------
// Bilinear over Linv. TWO consecutive (b,z,u) per block (shared b -> shared
// phi prologue). Nontemporal loads (A/B-verified: worth ~3 us vs plain).
// NEW: the it=0 pair of L-loads is issued BEFORE the LDS staging so the
// HBM stream starts under the prologue (compiler won't hoist loads past
// __syncthreads on its own).
// ---------------------------------------------------------------------------
__global__ __launch_bounds__(256) void bilinear_kernel(
    const float* __restrict__ Linv, const float* __restrict__ Q,
    const float* __restrict__ pphi, const float* __restrict__ b4,
    const float* __restrict__ logSigEps,
    float* __restrict__ out_mu, float* __restrict__ out_cov) {
    __shared__ __align__(16) float Ps[PP];
    __shared__ __align__(16) float Qs0[PP];
    __shared__ __align__(16) float Qs1[PP];
    __shared__ float red[16];

    const int bzu0 = blockIdx.x * 2;   // both matrices share b (64 % 2 == 0)
    const int bzu1 = bzu0 + 1;
    const int b    = bzu0 >> 6;
    const int tid  = threadIdx.x;

    const f32x4* LA = (const f32x4*)(Linv + (size_t)bzu0 * (PP * PP));
    const f32x4* LB = (const f32x4*)(Linv + (size_t)bzu1 * (PP * PP));

    // Start the stream immediately: it=0 loads issued before any LDS work.
    const f32x4 La0 = __builtin_nontemporal_load(LA + tid);
    const f32x4 Lb0 = __builtin_nontemporal_load(LB + tid);

    if (tid < 128) {
        Ps[tid] = b4[tid]
                + pphi[((size_t)0 * BB + b) * PP + tid]
                + pphi[((size_t)1 * BB + b) * PP + tid]
                + pphi[((size_t)2 * BB + b) * PP + tid]
                + pphi[((size_t)3 * BB + b) * PP + tid];
    } else if (tid < 160) {
        ((f32x4*)Qs0)[tid - 128] = ((const f32x4*)(Q + (size_t)bzu0 * PP))[tid - 128];
    } else if (tid < 192) {
        ((f32x4*)Qs1)[tid - 160] = ((const f32x4*)(Q + (size_t)bzu1 * PP))[tid - 160];
    }
    __syncthreads();

    const int j0 = (tid & 31) << 2;            // constant across iterations
    const f32x4 q0 = *(const f32x4*)(Qs0 + j0);
    const f32x4 q1 = *(const f32x4*)(Qs1 + j0);
    const f32x4 p  = *(const f32x4*)(Ps + j0);

    float accM0, accS0, accM1, accS1;
    {   // it = 0 with the preloaded registers
        const float pi = Ps[tid >> 5];
        const float sm0 = La0.x * q0.x + La0.y * q0.y + La0.z * q0.z + La0.w * q0.w;
        const float sp0 = La0.x * p.x  + La0.y * p.y  + La0.z * p.z  + La0.w * p.w;
        const float sm1 = Lb0.x * q1.x + Lb0.y * q1.y + Lb0.z * q1.z + Lb0.w * q1.w;
        const float sp1 = Lb0.x * p.x  + Lb0.y * p.y  + Lb0.z * p.z  + Lb0.w * p.w;
        accM0 = pi * sm0;  accS0 = pi * sp0;
        accM1 = pi * sm1;  accS1 = pi * sp1;
    }
    #pragma unroll
    for (int it = 1; it < 16; ++it) {
        const int f = it * 256 + tid;          // float4 index within a matrix
        const f32x4 La = __builtin_nontemporal_load(LA + f);
        const f32x4 Lb = __builtin_nontemporal_load(LB + f);
        const float pi = Ps[f >> 5];           // LDS broadcast (2 addrs/wave)
        const float sm0 = La.x * q0.x + La.y * q0.y + La.z * q0.z + La.w * q0.w;
        const float sp0 = La.x * p.x  + La.y * p.y  + La.z * p.z  + La.w * p.w;
        const float sm1 = Lb.x * q1.x + Lb.y * q1.y + Lb.z * q1.z + Lb.w * q1.w;
        const float sp1 = Lb.x * p.x  + Lb.y * p.y  + Lb.z * p.z  + Lb.w * p.w;
        accM0 = fmaf(pi, sm0, accM0);
        accS0 = fmaf(pi, sp0, accS0);
        accM1 = fmaf(pi, sm1, accM1);
        accS1 = fmaf(pi, sp1, accS1);
    }

    for (int off = 32; off; off >>= 1) {
        accM0 += __shfl_down(accM0, off, 64);
        accS0 += __shfl_down(accS0, off, 64);
        accM1 += __shfl_down(accM1, off, 64);
        accS1 += __shfl_down(accS1, off, 64);
    }
    const int wid = tid >> 6;
    if ((tid & 63) == 0) {
        red[wid]      = accM0; red[4 + wid]  = accS0;
        red[8 + wid]  = accM1; red[12 + wid] = accS1;
    }
    __syncthreads();
    if (tid == 0) {
        const float m0 = (red[0] + red[1]) + (red[2] + red[3]);
        const float s0 = (red[4] + red[5]) + (red[6] + red[7]);
        const float m1 = (red[8] + red[9]) + (red[10] + red[11]);
        const float s1 = (red[12] + red[13]) + (red[14] + red[15]);
        out_mu[bzu0]  = m0;
        out_cov[bzu0] = expf(logSigEps[bzu0 & 7]) * (1.f + s0);
        out_mu[bzu1]  = m1;
        out_cov[bzu1] = expf(logSigEps[bzu1 & 7]) * (1.f + s1);
    }
}

extern "C" void kernel_launch(void* const* d_in, const int* in_sizes, int n_in,
                              void* d_out, int out_size, void* d_ws, size_t ws_size,
                              hipStream_t stream) {
    const float* x         = (const float*)d_in[0];
    const float* Linv      = (const float*)d_in[1];
    const float* Q         = (const float*)d_in[2];
    const float* W1        = (const float*)d_in[3];
    const float* b1        = (const float*)d_in[4];
    const float* W2        = (const float*)d_in[5];
    const float* b2        = (const float*)d_in[6];
    const float* W3        = (const float*)d_in[7];
    const float* b3        = (const float*)d_in[8];
    const float* W4        = (const float*)d_in[9];
    const float* b4        = (const float*)d_in[10];
    const float* logSigEps = (const float*)d_in[11];

    float* ws   = (float*)d_ws;
    float* h2   = ws;                 // 64*512
    float* pphi = ws + BB * HH;       // 4*64*128

    l12_kernel<<<dim3(4, BB), 256, 0, stream>>>(x, W1, b1, W2, b2, h2);
    l34_kernel<<<dim3(4, BB), 256, 0, stream>>>(h2, W3, b3, W4, pphi);

    float* out_mu  = (float*)d_out;          // (B,Z,U,1) = 4096 floats
    float* out_cov = out_mu + BB * ZZ * UU;  // (B,Z,U)   = 4096 floats

    bilinear_kernel<<<(BB * ZZ * UU) / 2, 256, 0, stream>>>(
        Linv, Q, pphi, b4, logSigEps, out_mu, out_cov);
}

// Round 13
// 58.653 us; speedup vs baseline: 1.0529x; 1.0090x over previous
//
#include <hip/hip_runtime.h>
#include <math.h>

#define BB 64
#define ZZ 8
#define UU 8
#define PP 128
#define XX 64
#define HH 512

typedef float f32x4 __attribute__((ext_vector_type(4)));
typedef float f32x2 __attribute__((ext_vector_type(2)));

__device__ __forceinline__ float elu(float v) {
    return v > 0.f ? v : (expf(v) - 1.f);
}

// ---------------------------------------------------------------------------
// One 128-col chunk of a GEMV layer: out[0..128) = act(hs @ W[:, c0+..] + bias).
// hs = full input row in LDS (K floats). 256 threads = 32 f32x4 column
// groups x 8 K-slices; red padded (33-stride) to kill the reduce conflict.
// ---------------------------------------------------------------------------
template<int K, bool ELU>
__device__ __forceinline__ void chunk_gemv(
    const float* __restrict__ hs, const float* __restrict__ W,
    const float* __restrict__ biasC0, float* __restrict__ out,
    int N, int c0, int tid, f32x4* __restrict__ red) {
    constexpr int KPER = K / 8;
    const int g    = tid & 31;
    const int ks   = tid >> 5;
    const int kBeg = ks * KPER;
    const float* Wp = W + (size_t)kBeg * N + c0 + g * 4;

    f32x4 acc = {0.f, 0.f, 0.f, 0.f};
    #pragma unroll 8
    for (int k = 0; k < KPER; ++k) {
        const f32x4 w = *(const f32x4*)(Wp + (size_t)k * N);
        const float s = hs[kBeg + k];
        acc.x = fmaf(s, w.x, acc.x);
        acc.y = fmaf(s, w.y, acc.y);
        acc.z = fmaf(s, w.z, acc.z);
        acc.w = fmaf(s, w.w, acc.w);
    }
    red[ks * 33 + g] = acc;
    __syncthreads();

    if (tid < 32) {
        f32x4 a = red[tid];
        #pragma unroll
        for (int s2 = 1; s2 < 8; ++s2) {
            const f32x4 b = red[s2 * 33 + tid];
            a.x += b.x; a.y += b.y; a.z += b.z; a.w += b.w;
        }
        const f32x4 bb = *(const f32x4*)(biasC0 + tid * 4);
        a.x += bb.x; a.y += bb.y; a.z += bb.z; a.w += bb.w;
        if (ELU) { a.x = elu(a.x); a.y = elu(a.y); a.z = elu(a.z); a.w = elu(a.w); }
        *(f32x4*)(out + tid * 4) = a;
    }
    __syncthreads();
}

// ---------------------------------------------------------------------------
// Layers 1+2 fused: grid (4, 64). Each block recomputes the full h1 row
// (W1 is 128 KB, L2-shared -> ~free), then its 128-col chunk of h2.
// ---------------------------------------------------------------------------
__global__ __launch_bounds__(256) void l12_kernel(
    const float* __restrict__ x,
    const float* __restrict__ W1, const float* __restrict__ b1,
    const float* __restrict__ W2, const float* __restrict__ b2,
    float* __restrict__ h2buf) {
    __shared__ __align__(16) float xs[XX];
    __shared__ __align__(16) float hs[HH];
    __shared__ __align__(16) f32x4 red[8 * 33];

    const int tid = threadIdx.x;
    const int r   = blockIdx.y;
    const int c0  = blockIdx.x * 128;

    if (tid < XX) xs[tid] = x[(size_t)r * XX + tid];
    __syncthreads();

    {   // h1 full row: thread tid -> cols 2tid, 2tid+1
        const f32x2* W = (const f32x2*)W1;   // [XX][HH/2]
        f32x2 a0 = {0.f, 0.f}, a1 = {0.f, 0.f};
        #pragma unroll 8
        for (int k = 0; k < XX; k += 2) {
            const f32x2 w0 = W[(k + 0) * (HH / 2) + tid];
            const f32x2 w1 = W[(k + 1) * (HH / 2) + tid];
            const float s0 = xs[k + 0], s1 = xs[k + 1];
            a0.x = fmaf(s0, w0.x, a0.x); a0.y = fmaf(s0, w0.y, a0.y);
            a1.x = fmaf(s1, w1.x, a1.x); a1.y = fmaf(s1, w1.y, a1.y);
        }
        const f32x2 bb = ((const f32x2*)b1)[tid];
        hs[2 * tid + 0] = elu(a0.x + a1.x + bb.x);
        hs[2 * tid + 1] = elu(a0.y + a1.y + bb.y);
    }
    __syncthreads();

    chunk_gemv<HH, true>(hs, W2, b2 + c0, h2buf + (size_t)r * HH + c0, HH, c0, tid, red);
}

// ---------------------------------------------------------------------------
// Layer 3 + partial-phi: grid (4, 64). Block (c,r) stages the h2 row,
// computes h3 cols [c*128,(c+1)*128) into LDS (never hits global), then
// pphi[c][r][:] = h3_chunk @ W4[c*128:(c+1)*128, :]  (64 KB of W4/block).
// ---------------------------------------------------------------------------
__global__ __launch_bounds__(256) void l34_kernel(
    const float* __restrict__ h2buf,
    const float* __restrict__ W3, const float* __restrict__ b3,
    const float* __restrict__ W4,
    float* __restrict__ pphi) {
    __shared__ __align__(16) float hs[HH];
    __shared__ __align__(16) float hs3[128];
    __shared__ __align__(16) f32x4 red[8 * 33];
    __shared__ float red2[2][128];

    const int tid = threadIdx.x;
    const int r   = blockIdx.y;
    const int c   = blockIdx.x;
    const int c0  = c * 128;

    ((f32x2*)hs)[tid] = ((const f32x2*)(h2buf + (size_t)r * HH))[tid];
    __syncthreads();

    chunk_gemv<HH, true>(hs, W3, b3 + c0, hs3, HH, c0, tid, red);

    {   // partial phi: 2 k-slices x 128 cols
        const int j    = tid & 127;
        const int half = tid >> 7;
        const int kBeg = half * 64;
        const float* Wp = W4 + (size_t)(c0 + kBeg) * PP + j;
        float acc = 0.f;
        #pragma unroll 8
        for (int k = 0; k < 64; ++k)
            acc = fmaf(hs3[kBeg + k], Wp[(size_t)k * PP], acc);
        red2[half][j] = acc;
    }
    __syncthreads();
    if (tid < 128)
        pphi[((size_t)c * BB + r) * PP + tid] = red2[0][tid] + red2[1][tid];
}

// ---------------------------------------------------------------------------
// Bilinear over Linv. TWO consecutive (b,z,u) per block (shared b -> shared
// phi prologue). Nontemporal loads (A/B-verified vs plain: worth ~3 us --
// no-allocate avoids L2 fill/evict work on a zero-reuse stream). This exact
// configuration is the best of 6 measured variants (58.3 us):
//   1/blk=60.2, 2/blk+plain=61.2, 2/blk+preload=58.7, 4/blk+lb2=61.8,
//   2/blk+hoist=59.2.
// ---------------------------------------------------------------------------
__global__ __launch_bounds__(256) void bilinear_kernel(
    const float* __restrict__ Linv, const float* __restrict__ Q,
    const float* __restrict__ pphi, const float* __restrict__ b4,
    const float* __restrict__ logSigEps,
    float* __restrict__ out_mu, float* __restrict__ out_cov) {
    __shared__ __align__(16) float Ps[PP];
    __shared__ __align__(16) float Qs0[PP];
    __shared__ __align__(16) float Qs1[PP];
    __shared__ float red[16];

    const int bzu0 = blockIdx.x * 2;   // both matrices share b (64 % 2 == 0)
    const int bzu1 = bzu0 + 1;
    const int b    = bzu0 >> 6;
    const int tid  = threadIdx.x;

    if (tid < 128) {
        Ps[tid] = b4[tid]
                + pphi[((size_t)0 * BB + b) * PP + tid]
                + pphi[((size_t)1 * BB + b) * PP + tid]
                + pphi[((size_t)2 * BB + b) * PP + tid]
                + pphi[((size_t)3 * BB + b) * PP + tid];
    } else if (tid < 160) {
        ((f32x4*)Qs0)[tid - 128] = ((const f32x4*)(Q + (size_t)bzu0 * PP))[tid - 128];
    } else if (tid < 192) {
        ((f32x4*)Qs1)[tid - 160] = ((const f32x4*)(Q + (size_t)bzu1 * PP))[tid - 160];
    }
    __syncthreads();

    const int j0 = (tid & 31) << 2;            // constant across iterations
    const f32x4 q0 = *(const f32x4*)(Qs0 + j0);
    const f32x4 q1 = *(const f32x4*)(Qs1 + j0);
    const f32x4 p  = *(const f32x4*)(Ps + j0);

    const f32x4* LA = (const f32x4*)(Linv + (size_t)bzu0 * (PP * PP));
    const f32x4* LB = (const f32x4*)(Linv + (size_t)bzu1 * (PP * PP));
    float accM0 = 0.f, accS0 = 0.f, accM1 = 0.f, accS1 = 0.f;
    #pragma unroll
    for (int it = 0; it < 16; ++it) {
        const int f = it * 256 + tid;          // float4 index within a matrix
        const f32x4 La = __builtin_nontemporal_load(LA + f);
        const f32x4 Lb = __builtin_nontemporal_load(LB + f);
        const float pi = Ps[f >> 5];           // LDS broadcast (2 addrs/wave)
        const float sm0 = La.x * q0.x + La.y * q0.y + La.z * q0.z + La.w * q0.w;
        const float sp0 = La.x * p.x  + La.y * p.y  + La.z * p.z  + La.w * p.w;
        const float sm1 = Lb.x * q1.x + Lb.y * q1.y + Lb.z * q1.z + Lb.w * q1.w;
        const float sp1 = Lb.x * p.x  + Lb.y * p.y  + Lb.z * p.z  + Lb.w * p.w;
        accM0 = fmaf(pi, sm0, accM0);
        accS0 = fmaf(pi, sp0, accS0);
        accM1 = fmaf(pi, sm1, accM1);
        accS1 = fmaf(pi, sp1, accS1);
    }

    for (int off = 32; off; off >>= 1) {
        accM0 += __shfl_down(accM0, off, 64);
        accS0 += __shfl_down(accS0, off, 64);
        accM1 += __shfl_down(accM1, off, 64);
        accS1 += __shfl_down(accS1, off, 64);
    }
    const int wid = tid >> 6;
    if ((tid & 63) == 0) {
        red[wid]      = accM0; red[4 + wid]  = accS0;
        red[8 + wid]  = accM1; red[12 + wid] = accS1;
    }
    __syncthreads();
    if (tid == 0) {
        const float m0 = (red[0] + red[1]) + (red[2] + red[3]);
        const float s0 = (red[4] + red[5]) + (red[6] + red[7]);
        const float m1 = (red[8] + red[9]) + (red[10] + red[11]);
        const float s1 = (red[12] + red[13]) + (red[14] + red[15]);
        out_mu[bzu0]  = m0;
        out_cov[bzu0] = expf(logSigEps[bzu0 & 7]) * (1.f + s0);
        out_mu[bzu1]  = m1;
        out_cov[bzu1] = expf(logSigEps[bzu1 & 7]) * (1.f + s1);
    }
}

extern "C" void kernel_launch(void* const* d_in, const int* in_sizes, int n_in,
                              void* d_out, int out_size, void* d_ws, size_t ws_size,
                              hipStream_t stream) {
    const float* x         = (const float*)d_in[0];
    const float* Linv      = (const float*)d_in[1];
    const float* Q         = (const float*)d_in[2];
    const float* W1        = (const float*)d_in[3];
    const float* b1        = (const float*)d_in[4];
    const float* W2        = (const float*)d_in[5];
    const float* b2        = (const float*)d_in[6];
    const float* W3        = (const float*)d_in[7];
    const float* b3        = (const float*)d_in[8];
    const float* W4        = (const float*)d_in[9];
    const float* b4        = (const float*)d_in[10];
    const float* logSigEps = (const float*)d_in[11];

    float* ws   = (float*)d_ws;
    float* h2   = ws;                 // 64*512
    float* pphi = ws + BB * HH;       // 4*64*128

    l12_kernel<<<dim3(4, BB), 256, 0, stream>>>(x, W1, b1, W2, b2, h2);
    l34_kernel<<<dim3(4, BB), 256, 0, stream>>>(h2, W3, b3, W4, pphi);

    float* out_mu  = (float*)d_out;          // (B,Z,U,1) = 4096 floats
    float* out_cov = out_mu + BB * ZZ * UU;  // (B,Z,U)   = 4096 floats

    bilinear_kernel<<<(BB * ZZ * UU) / 2, 256, 0, stream>>>(
        Linv, Q, pphi, b4, logSigEps, out_mu, out_cov);
}